// Round 5
// baseline (291.303 us; speedup 1.0000x reference)
//
#include <hip/hip_runtime.h>

// Problem constants (B=8, N=256, DIN=DOUT=EIN=EOUT=64)
#define BN   2048      // B*N
#define NN   256       // N
#define CH   64        // channel dims

typedef __attribute__((ext_vector_type(8))) short short8;   // 8 bf16
typedef __attribute__((ext_vector_type(4))) float fv4;

// fp32 -> bf16 bits, round-to-nearest-even
static __device__ inline short f2bf(float f) {
  unsigned u = __float_as_uint(f);
  u += 0x7FFF + ((u >> 16) & 1);
  return (short)(u >> 16);
}

// 8 fp32 -> short8 bf16 via packed cvt (RNE), 4 instrs
static __device__ inline short8 cvt_frag(fv4 a, fv4 b) {
  union { short8 s; unsigned u[4]; } r;
  asm("v_cvt_pk_bf16_f32 %0, %1, %2" : "=v"(r.u[0]) : "v"(a[0]), "v"(a[1]));
  asm("v_cvt_pk_bf16_f32 %0, %1, %2" : "=v"(r.u[1]) : "v"(a[2]), "v"(a[3]));
  asm("v_cvt_pk_bf16_f32 %0, %1, %2" : "=v"(r.u[2]) : "v"(b[0]), "v"(b[1]));
  asm("v_cvt_pk_bf16_f32 %0, %1, %2" : "=v"(r.u[3]) : "v"(b[2]), "v"(b[3]));
  return r.s;
}

// ---------------------------------------------------------------------------
// Kernel 1: node_x = emb_node@Wn + bn (fp32), rsx = relu(emb_node@Wsn + bsn).
// ---------------------------------------------------------------------------
__global__ __launch_bounds__(256) void node_kernel(
    const float* __restrict__ emb_node, const float* __restrict__ Wn,
    const float* __restrict__ bn, const float* __restrict__ Wsn,
    const float* __restrict__ bsn, float* __restrict__ node_x,
    float* __restrict__ rsx) {
  __shared__ float s_emb[4][CH];
  __shared__ float s_Wn[CH * CH];   // 16 KB
  __shared__ float s_Ws[CH * CH];   // 16 KB
  const int tid = threadIdx.x;
  const int r = tid >> 6;
  const int c = tid & 63;
  const int row = blockIdx.x * 4 + r;
#pragma unroll
  for (int i = 0; i < 4; ++i) {
    *(fv4*)&s_Wn[(i * 256 + tid) * 4] = *(const fv4*)&Wn[(i * 256 + tid) * 4];
    *(fv4*)&s_Ws[(i * 256 + tid) * 4] = *(const fv4*)&Wsn[(i * 256 + tid) * 4];
  }
  s_emb[r][c] = emb_node[row * CH + c];
  __syncthreads();
  float a1 = bn[c], a2 = bsn[c];
#pragma unroll
  for (int k = 0; k < CH; ++k) {
    const float e = s_emb[r][k];          // wave-uniform broadcast
    a1 = fmaf(e, s_Wn[k * CH + c], a1);
    a2 = fmaf(e, s_Ws[k * CH + c], a2);
  }
  node_x[row * CH + c] = a1;
  rsx[row * CH + c] = fmaxf(a2, 0.0f);
}

// ---------------------------------------------------------------------------
// Kernel 2, round 5: fully decoupled waves.
//   Block = (b,i); wave w = col-strip [16w,16w+16) x ALL 256 rows.
//   NO LDS, NO barriers, NO atomics. Each 16-row tile is a single-shot
//   load->MFMA->store; latency hidden by TLP: <=64 VGPR (launch_bounds
//   (256,8)) -> 8 waves/SIMD, whole grid co-resident.
//   A-fragments loaded straight from global (row=l15, k=quad*8 slices --
//   verified m89 mapping, same as the LDS path of rounds 0/4). The 4x
//   intra-block re-read of each 4KB emb tile is served by L1/L2.
//   agg is wave-local (own cols): 2x shfl_xor at the end, direct store.
//   edge_out: nontemporal stores (written once, never read) -> keeps
//   emb_edge L3-resident across bench iterations.
// ---------------------------------------------------------------------------
__global__ __launch_bounds__(256, 8) void edge_mfma_kernel(
    const float* __restrict__ A, const float* __restrict__ emb_edge,
    const float* __restrict__ We, const float* __restrict__ be,
    const float* __restrict__ node_x, const float* __restrict__ rsx,
    float* __restrict__ node_out, float* __restrict__ edge_out) {
  const int bi   = blockIdx.x;         // b*N + i
  const int b    = bi >> 8;
  const int tid  = threadIdx.x;
  const int lane = tid & 63;
  const int wave = tid >> 6;           // 0..3 -> col tile
  const int l15  = lane & 15;
  const int quad = lane >> 4;
  const int c    = wave * 16 + l15;

  const float* __restrict__ ee = emb_edge + (size_t)bi * NN * CH;
  float*       __restrict__ eo = edge_out + (size_t)bi * NN * CH;
  const float* __restrict__ nx = node_x + (size_t)b * NN * CH;
  const float* __restrict__ Ar = A + (size_t)bi * NN;

  // We fragments (col c) + bias: one-time, 16 scalar loads
  short8 bfrag[2];
#pragma unroll
  for (int h = 0; h < 2; ++h)
#pragma unroll
    for (int j = 0; j < 8; ++j)
      bfrag[h][j] = f2bf(We[(h * 32 + quad * 8 + j) * CH + c]);
  const float bias = be[c];

  float agg = 0.0f;

  for (int t = 0; t < 16; ++t) {
    const int j0 = t * 16;
    // A-operand: row = j0 + l15, k = quad*8..+8 and 32+quad*8..+8
    const float* rp = ee + (j0 + l15) * CH + quad * 8;
    const fv4 a0 = *(const fv4*)(rp);
    const fv4 a1 = *(const fv4*)(rp + 4);
    const fv4 a2 = *(const fv4*)(rp + 32);
    const fv4 a3 = *(const fv4*)(rp + 36);
    // epilogue operands (independent loads, same wait)
    const fv4 av = *(const fv4*)(Ar + j0 + quad * 4);   // quad-uniform
    const int rb = j0 + quad * 4;
    float nxv[4];
#pragma unroll
    for (int r = 0; r < 4; ++r) nxv[r] = nx[(rb + r) * CH + c];

    const short8 af0 = cvt_frag(a0, a1);
    const short8 af1 = cvt_frag(a2, a3);
    fv4 acc = {bias, bias, bias, bias};                 // bias as C-in
    acc = __builtin_amdgcn_mfma_f32_16x16x32_bf16(af0, bfrag[0], acc, 0, 0, 0);
    acc = __builtin_amdgcn_mfma_f32_16x16x32_bf16(af1, bfrag[1], acc, 0, 0, 0);
#pragma unroll
    for (int r = 0; r < 4; ++r) {
      const float ex = acc[r];                          // pre-relu edge_x
      __builtin_nontemporal_store(fmaxf(ex, 0.0f), eo + (rb + r) * CH + c);
      agg = fmaf(av[r] * ex, nxv[r], agg);
    }
  }

  // rows are split across quads only: 2 shfl_xor completes the 256-row sum
  agg += __shfl_xor(agg, 16, 64);
  agg += __shfl_xor(agg, 32, 64);
  if (quad == 0) {
    node_out[(size_t)bi * CH + c] =
        fmaxf(agg, 0.0f) + rsx[(size_t)bi * CH + c];
  }
}

// ---------------------------------------------------------------------------
extern "C" void kernel_launch(void* const* d_in, const int* in_sizes, int n_in,
                              void* d_out, int out_size, void* d_ws, size_t ws_size,
                              hipStream_t stream) {
  const float* A        = (const float*)d_in[0];  // [8,256,256]
  const float* emb_node = (const float*)d_in[1];  // [8,256,64]
  const float* emb_edge = (const float*)d_in[2];  // [8,256,256,64]
  const float* Wn       = (const float*)d_in[3];  // [64,64]
  const float* bn       = (const float*)d_in[4];  // [64]
  const float* Wsn      = (const float*)d_in[5];  // [64,64]
  const float* bsn      = (const float*)d_in[6];  // [64]
  const float* We       = (const float*)d_in[7];  // [64,64]
  const float* be       = (const float*)d_in[8];  // [64]

  float* node_out = (float*)d_out;                     // [2048,64]
  float* edge_out = (float*)d_out + (size_t)BN * CH;   // [2048,256,64]

  float* node_x = (float*)d_ws;                        // [2048,64] fp32
  float* rsx    = (float*)d_ws + (size_t)BN * CH;      // [2048,64] fp32

  hipLaunchKernelGGL(node_kernel, dim3(BN / 4), dim3(256), 0, stream,
                     emb_node, Wn, bn, Wsn, bsn, node_x, rsx);
  hipLaunchKernelGGL(edge_mfma_kernel, dim3(BN), dim3(256), 0, stream,
                     A, emb_edge, We, be, node_x, rsx, node_out, edge_out);
}

// Round 6
// 261.132 us; speedup vs baseline: 1.1155x; 1.1155x over previous
//
#include <hip/hip_runtime.h>

// Problem constants (B=8, N=256, DIN=DOUT=EIN=EOUT=64)
#define BN   2048      // B*N
#define NN   256       // N
#define CH   64        // channel dims

typedef __attribute__((ext_vector_type(8))) short short8;   // 8 bf16
typedef __attribute__((ext_vector_type(4))) float fv4;

// fp32 -> bf16 bits, round-to-nearest-even (We prologue only)
static __device__ inline short f2bf(float f) {
  unsigned u = __float_as_uint(f);
  u += 0x7FFF + ((u >> 16) & 1);
  return (short)(u >> 16);
}

// 8 fp32 -> short8 bf16 via packed cvt (RNE), 4 instrs
static __device__ inline short8 cvt_frag(fv4 a, fv4 b) {
  union { short8 s; unsigned u[4]; } r;
  asm("v_cvt_pk_bf16_f32 %0, %1, %2" : "=v"(r.u[0]) : "v"(a[0]), "v"(a[1]));
  asm("v_cvt_pk_bf16_f32 %0, %1, %2" : "=v"(r.u[1]) : "v"(a[2]), "v"(a[3]));
  asm("v_cvt_pk_bf16_f32 %0, %1, %2" : "=v"(r.u[2]) : "v"(b[0]), "v"(b[1]));
  asm("v_cvt_pk_bf16_f32 %0, %1, %2" : "=v"(r.u[3]) : "v"(b[2]), "v"(b[3]));
  return r.s;
}

// global -> LDS DMA, 16B per lane. LDS dest = wave-uniform base + lane*16;
// global src is PER-LANE (pre-swizzled for bank-conflict-free reads, m173).
#define GLOAD16(gp, lp)                                                        \
  __builtin_amdgcn_global_load_lds(                                            \
      (const __attribute__((address_space(1))) unsigned*)(gp),                 \
      (__attribute__((address_space(3))) unsigned*)(lp), 16, 0, 0)

#define WAITV(N) asm volatile("s_waitcnt vmcnt(" #N ")" ::: "memory")

// ---------------------------------------------------------------------------
// Kernel 1: node_x = emb_node@Wn + bn (fp32), rsx = relu(emb_node@Wsn + bsn).
// ---------------------------------------------------------------------------
__global__ __launch_bounds__(256) void node_kernel(
    const float* __restrict__ emb_node, const float* __restrict__ Wn,
    const float* __restrict__ bn, const float* __restrict__ Wsn,
    const float* __restrict__ bsn, float* __restrict__ node_x,
    float* __restrict__ rsx) {
  __shared__ float s_emb[4][CH];
  __shared__ float s_Wn[CH * CH];   // 16 KB
  __shared__ float s_Ws[CH * CH];   // 16 KB
  const int tid = threadIdx.x;
  const int r = tid >> 6;
  const int c = tid & 63;
  const int row = blockIdx.x * 4 + r;
#pragma unroll
  for (int i = 0; i < 4; ++i) {
    *(fv4*)&s_Wn[(i * 256 + tid) * 4] = *(const fv4*)&Wn[(i * 256 + tid) * 4];
    *(fv4*)&s_Ws[(i * 256 + tid) * 4] = *(const fv4*)&Wsn[(i * 256 + tid) * 4];
  }
  s_emb[r][c] = emb_node[row * CH + c];
  __syncthreads();
  float a1 = bn[c], a2 = bsn[c];
#pragma unroll
  for (int k = 0; k < CH; ++k) {
    const float e = s_emb[r][k];          // wave-uniform broadcast
    a1 = fmaf(e, s_Wn[k * CH + c], a1);
    a2 = fmaf(e, s_Ws[k * CH + c], a2);
  }
  node_x[row * CH + c] = a1;
  rsx[row * CH + c] = fmaxf(a2, 0.0f);
}

// ---------------------------------------------------------------------------
// Kernel 2, round 6: round-4 DMA skeleton + SWAPPED MFMA operands.
//   D = mfma(We_frag, emb_frag): lane (quad,l15) -> row j = j0+l15,
//   cols c = 16w + quad*4 + {0..3}  (operand-layout symmetry: both frags
//   use l15 as M/N index, quad*8 as K slice -- verified by r0/r4 refcheck).
//   => edge_out store = ONE dwordx4 (16B/lane) per half-chunk (was 8 scalar)
//      -> 4x fewer store-retirement events in the in-order vmcnt stream,
//         which gate every chunk wait (the round-0/2/4 82us invariant).
//   => nx gather = one ds_read_b128 (was 4 ds_read_b32).
//   Staging/swizzle/barrier structure identical to round 4 (verified).
//   vmcnt recounted for 2 stores/chunk/wave.
// ---------------------------------------------------------------------------
__global__ __launch_bounds__(256, 4) void edge_mfma_kernel(
    const float* __restrict__ A, const float* __restrict__ emb_edge,
    const float* __restrict__ We, const float* __restrict__ be,
    const float* __restrict__ node_x, const float* __restrict__ rsx,
    float* __restrict__ node_out, float* __restrict__ edge_out) {
  const int bi   = blockIdx.x;         // b*N + i
  const int b    = bi >> 8;
  const int tid  = threadIdx.x;
  const int lane = tid & 63;
  const int wave = tid >> 6;           // 0..3 -> col tile [16w,16w+16)
  const int l15  = lane & 15;
  const int quad = lane >> 4;
  const int cq   = wave * 16 + quad * 4;   // first of this lane's 4 cols

  // 3-deep chunk buffers: 32 rows x 64 fp32 = 8 KB each
  __shared__ __align__(16) float s_e[3][2048];   // emb_edge (swizzled)
  __shared__ __align__(16) float s_n[3][2048];   // node_x   (swizzled)
  __shared__ __align__(16) float s_Af[NN];       // A row (linear)

  const float* __restrict__ ee = emb_edge + (size_t)bi * NN * CH;
  float*       __restrict__ eo = edge_out + (size_t)bi * NN * CH;
  const float* __restrict__ nx = node_x + (size_t)b * NN * CH;

  // ---- A row (plain load + ds_write; single writer per byte) ----
  const float aval = A[(size_t)bi * NN + tid];
  s_Af[tid] = aval;

  // ---- We fragments + bias (drained by use before DMA begins) ----
  // wfrag supplies, as MFMA arg0 (A-operand): A[m=l15][k=quad*8+j] =
  // We[k][wave*16 + l15]  (same element set as rounds 0/4).
  short8 wfrag[2];
#pragma unroll
  for (int h = 0; h < 2; ++h)
#pragma unroll
    for (int j = 0; j < 8; ++j)
      wfrag[h][j] = f2bf(We[(h * 32 + quad * 8 + j) * CH + wave * 16 + l15]);
  const fv4 biasv = *(const fv4*)&be[cq];    // cols cq..cq+3 (16B aligned)

  // ---- per-lane offsets (identical staging math to round 4) ----
  // staging: lane covers LDS bytes o = wave*2048 + s*1024 + lane*16;
  // row = o>>8, ib = o&255; swizzled src = row*256 + (ib ^ ((row&15)<<4))
  const int rowA = wave * 8 + (lane >> 4);
  const int rowB = rowA + 4;
  const int ibq  = (lane & 15) * 16;
  const int offA = rowA * 256 + (ibq ^ ((rowA & 15) << 4));
  const int offB = rowB * 256 + (ibq ^ ((rowB & 15) << 4));
  // emb frag reads: chunk-local row rr = h*16+l15 -> rr&15 = l15
  const int swz = l15 << 4;
  const int o0 = (quad * 32) ^ swz;          // k = quad*8 .. +3
  const int o1 = (quad * 32 + 16) ^ swz;     // k = quad*8+4 .. +7
  const int o2 = (128 + quad * 32) ^ swz;    // k = 32+quad*8 ..
  const int o3 = (144 + quad * 32) ^ swz;
  // nx fv4 read: row rr = h*16+l15, cols cq..cq+3 -> 16B at (cq*4)^swz
  const int nxo = (cq * 4) ^ swz;

#define STAGE(T, D)                                                            \
  {                                                                            \
    const char* eb_ = (const char*)ee + (T) * 8192;                            \
    const char* nb_ = (const char*)nx + (T) * 8192;                            \
    GLOAD16(eb_ + offA, (char*)&s_e[(D)][0] + wave * 2048);                    \
    GLOAD16(eb_ + offB, (char*)&s_e[(D)][0] + wave * 2048 + 1024);             \
    GLOAD16(nb_ + offA, (char*)&s_n[(D)][0] + wave * 2048);                    \
    GLOAD16(nb_ + offB, (char*)&s_n[(D)][0] + wave * 2048 + 1024);             \
  }

  STAGE(0, 0)
  STAGE(1, 1)

  fv4 agg = {0.f, 0.f, 0.f, 0.f};   // cols cq..cq+3, partial over j=l15 rows

#define COMPUTE(CHK, D)                                                        \
  {                                                                            \
    _Pragma("unroll") for (int h = 0; h < 2; ++h) {                            \
      const char* eb_ = (const char*)&s_e[(D)][0] + (h * 16 + l15) * 256;      \
      const fv4 a0 = *(const fv4*)(eb_ + o0);                                  \
      const fv4 a1 = *(const fv4*)(eb_ + o1);                                  \
      const fv4 a2 = *(const fv4*)(eb_ + o2);                                  \
      const fv4 a3 = *(const fv4*)(eb_ + o3);                                  \
      const short8 af0 = cvt_frag(a0, a1);                                     \
      const short8 af1 = cvt_frag(a2, a3);                                     \
      fv4 acc = biasv;                       /* bias as C-in */                \
      acc = __builtin_amdgcn_mfma_f32_16x16x32_bf16(wfrag[0], af0, acc, 0,0,0);\
      acc = __builtin_amdgcn_mfma_f32_16x16x32_bf16(wfrag[1], af1, acc, 0,0,0);\
      const int j = (CHK) * 32 + h * 16 + l15;       /* this lane's row */     \
      const float av = s_Af[j];                      /* 4-way bcast read */    \
      const fv4 nxv =                                                          \
          *(const fv4*)((const char*)&s_n[(D)][0] + h * 4096 +                 \
                        l15 * 256 + nxo);                                      \
      fv4 rl;                                                                  \
      _Pragma("unroll") for (int r = 0; r < 4; ++r) {                          \
        rl[r] = fmaxf(acc[r], 0.0f);                                           \
        agg[r] = fmaf(av * acc[r], nxv[r], agg[r]);                            \
      }                                                                        \
      *(fv4*)(eo + j * CH + cq) = rl;      /* ONE 16B store per half-chunk */  \
    }                                                                          \
  }

  // iteration = wait(own chunk DMA, counted) ; barrier ; stage k+2 ;
  // compute k.  vmcnt retires in order; counts include the 2 stores/chunk.
#define ITER(CHK, NW, PF)                                                      \
  {                                                                            \
    WAITV(NW);                                                                 \
    __builtin_amdgcn_s_barrier();                                              \
    if (PF) STAGE((CHK) + 2, ((CHK) + 2) % 3)                                  \
    asm volatile("" ::: "memory"); /* pin stage above stores */                \
    COMPUTE(CHK, (CHK) % 3)                                                    \
  }

  // first barrier also needs the s_Af ds_write visible
  asm volatile("s_waitcnt vmcnt(4) lgkmcnt(0)" ::: "memory");
  __builtin_amdgcn_s_barrier();
  STAGE(2, 2)
  asm volatile("" ::: "memory");
  COMPUTE(0, 0)

  ITER(1, 6, 1)   // newer than c1: stage2(4)+stores0(2)
  ITER(2, 8, 1)   // stores0(2)+stage3(4)+stores1(2)
  ITER(3, 8, 1)
  ITER(4, 8, 1)
  ITER(5, 8, 1)
  ITER(6, 8, 0)   // stores4(2)+stage7(4)+stores5(2)
  ITER(7, 4, 0)   // stores5(2)+stores6(2)

#undef ITER
#undef COMPUTE
#undef STAGE

  // agg[r] holds partial sums over this lane's rows (j = *,l15) for cols
  // cq..cq+3. Sum over the 16 l15 lanes (quad bits are col groups, kept).
#pragma unroll
  for (int r = 0; r < 4; ++r) {
    agg[r] += __shfl_xor(agg[r], 1, 64);
    agg[r] += __shfl_xor(agg[r], 2, 64);
    agg[r] += __shfl_xor(agg[r], 4, 64);
    agg[r] += __shfl_xor(agg[r], 8, 64);
  }
  if (l15 == 0) {
    const fv4 rs = *(const fv4*)&rsx[(size_t)bi * CH + cq];
    fv4 out;
#pragma unroll
    for (int r = 0; r < 4; ++r) out[r] = fmaxf(agg[r], 0.0f) + rs[r];
    *(fv4*)&node_out[(size_t)bi * CH + cq] = out;
  }
}

// ---------------------------------------------------------------------------
extern "C" void kernel_launch(void* const* d_in, const int* in_sizes, int n_in,
                              void* d_out, int out_size, void* d_ws, size_t ws_size,
                              hipStream_t stream) {
  const float* A        = (const float*)d_in[0];  // [8,256,256]
  const float* emb_node = (const float*)d_in[1];  // [8,256,64]
  const float* emb_edge = (const float*)d_in[2];  // [8,256,256,64]
  const float* Wn       = (const float*)d_in[3];  // [64,64]
  const float* bn       = (const float*)d_in[4];  // [64]
  const float* Wsn      = (const float*)d_in[5];  // [64,64]
  const float* bsn      = (const float*)d_in[6];  // [64]
  const float* We       = (const float*)d_in[7];  // [64,64]
  const float* be       = (const float*)d_in[8];  // [64]

  float* node_out = (float*)d_out;                     // [2048,64]
  float* edge_out = (float*)d_out + (size_t)BN * CH;   // [2048,256,64]

  float* node_x = (float*)d_ws;                        // [2048,64] fp32
  float* rsx    = (float*)d_ws + (size_t)BN * CH;      // [2048,64] fp32

  hipLaunchKernelGGL(node_kernel, dim3(BN / 4), dim3(256), 0, stream,
                     emb_node, Wn, bn, Wsn, bsn, node_x, rsx);
  hipLaunchKernelGGL(edge_mfma_kernel, dim3(BN), dim3(256), 0, stream,
                     A, emb_edge, We, be, node_x, rsx, node_out, edge_out);
}